// Round 8
// baseline (12560.043 us; speedup 1.0000x reference)
//
#include <hip/hip_runtime.h>

#define TT 2048
#define WD 768
#define HH 512
#define G4 2048      // 4*H
#define NC 5
#define SENT 0xFFFFFFFFu   // owned sentinel (-NaN); |h|<1 can never produce it.
                           // h buffers memset to 0xFF at every launch.

typedef float f4 __attribute__((ext_vector_type(4)));
typedef unsigned int u4 __attribute__((ext_vector_type(4)));

// ---------------------------------------------------------------------------
// ONE kernel, 577 wgs, role-claimed at runtime:
//   64 lstm wgs  : two groups of 32, each group pinned to ONE XCD (claim via
//                  s_getreg(XCC_ID) + atomic slots; CAS publication forces the
//                  two directions onto DISTINCT XCDs). R0 recurrence verbatim;
//                  NEW opportunistic fast path: producers dual-store h
//                  (plain -> hwl lands write-through in the LOCAL XCD L2;
//                  sc1 -> hw, the R0-proven LLC path). Consumers try <=24
//                  nt-flagged probes of hwl (nt = L1 no-allocate/evict, so a
//                  spin cannot be permanently served by a stale L1 line);
//                  per-lane persistent fastok falls back to the R0 base probe
//                  forever on first failure. Values identical either way.
//   512 gemm wgs : R6 overlay verbatim (sc1 stores + zcnt flags).
//   1 viterbi wg : waits for feats counter (sc1-drained), runs R7 viterbi.
//
// Deadlock analysis: launch_bounds(256,2) + 45.6KB LDS => >=2 wgs/CU => >=512
// of 577 wgs resident at t=0. <=280 claims cannot avoid two complete groups
// on two distinct XCDs (7*31+63=280<512), so the claim spin terminates.
// gemm wgs depend only on the claim; lstm on claim+zcnt(gemm)+h(dual-stored);
// viterbi on feats counter (unconditionally produced by lstm tails). No cycle.
// ---------------------------------------------------------------------------
__global__ __launch_bounds__(256, 2) void fused_all(
    const int* __restrict__ sent, const float* __restrict__ emb,
    const float* __restrict__ Wih_f, const float* __restrict__ bih_f, const float* __restrict__ bhh_f,
    const float* __restrict__ Wih_b, const float* __restrict__ bih_b, const float* __restrict__ bhh_b,
    const float* __restrict__ Whh_f, const float* __restrict__ Whh_b,
    float* __restrict__ zin_f, float* __restrict__ zin_b,
    unsigned int* __restrict__ hw_f, unsigned int* __restrict__ hw_b,
    unsigned int* __restrict__ hwl_f, unsigned int* __restrict__ hwl_b,
    unsigned int* __restrict__ zcnt, unsigned int* __restrict__ ctl,
    const float* __restrict__ fc_w, const float* __restrict__ fc_b,
    float* __restrict__ feats, const float* __restrict__ trans,
    float* __restrict__ out)
{
    __shared__ __align__(16) char SMEM[45568];
    __shared__ int s_role;
    const int tid = threadIdx.x;

    // ---- role claim -------------------------------------------------------
    // ctl (memset 0xFF): [0..7] per-XCD slot counters; [9],[10] dir tags;
    // [11] rest counter; [12] feats-done counter. (All start at -1/sentinel.)
    if (tid == 0) {
        unsigned int xcc;
        asm volatile("s_getreg_b32 %0, hwreg(20, 0, 32)" : "=s"(xcc)); // XCC_ID
        xcc &= 7u;
        const unsigned int slot = atomicAdd(&ctl[xcc], 1u) + 1u;
        const unsigned int grp = slot >> 5, lig = slot & 31u;
        const unsigned int mytag = 0x40000000u | (xcc << 8) | grp;  // never SENT
        if (lig == 31u) {                       // group completer
            if (atomicCAS(&ctl[9], SENT, mytag) != SENT) {
                // dir0 taken; claim dir1 only from a DIFFERENT XCD
                const unsigned int c0v = __hip_atomic_load(&ctl[9],
                        __ATOMIC_RELAXED, __HIP_MEMORY_SCOPE_AGENT);
                if (((c0v >> 8) & 7u) != xcc)
                    atomicCAS(&ctl[10], SENT, mytag);
            }
        }
        unsigned int c0, c1;
        do {
            c0 = __hip_atomic_load(&ctl[9],  __ATOMIC_RELAXED, __HIP_MEMORY_SCOPE_AGENT);
            c1 = __hip_atomic_load(&ctl[10], __ATOMIC_RELAXED, __HIP_MEMORY_SCOPE_AGENT);
        } while (c0 == SENT || c1 == SENT);     // terminates: see header
        int role;
        if      (c0 == mytag) role = (int)lig;         // dir0, k=lig
        else if (c1 == mytag) role = 32 + (int)lig;    // dir1, k=lig
        else    role = 64 + (int)(atomicAdd(&ctl[11], 1u) + 1u);  // 64..576
        s_role = role;
    }
    __syncthreads();
    const int role = s_role;

    if (role >= 64 && role < 576) {
        // ================= GEMM role (R6 verbatim) =================
        float (*As)[128] = (float(*)[128])SMEM;
        float (*Bs)[128] = (float(*)[128])(SMEM + 8192);
        const int lin  = role - 64;            // [0,512)
        const int pair = lin >> 5;
        const int sub  = lin & 31;
        const int dirn = sub & 1;
        const int gx   = sub >> 1;
        const int ty   = dirn ? (15 - pair) : pair;

        const float* Wih = dirn ? Wih_b : Wih_f;
        const float* bih = dirn ? bih_b : bih_f;
        const float* bhh = dirn ? bhh_b : bhh_f;
        float* zin = dirn ? zin_b : zin_f;

        const int t0 = ty * 128;
        const int g0 = gx * 128;
        const int tm = tid >> 4, tn = tid & 15;

        float acc[8][8];
#pragma unroll
        for (int a = 0; a < 8; a++)
#pragma unroll
            for (int b = 0; b < 8; b++) acc[a][b] = 0.f;

        for (int kt = 0; kt < 48; ++kt) {
            const int k0 = kt * 16;
#pragma unroll
            for (int u = 0; u < 2; ++u) {
                const int s = tid * 2 + u;
                const int m = s >> 2, kq = s & 3;
                const int rowA = sent[t0 + m];
                float4 av = *(const float4*)(emb + (size_t)rowA * WD + k0 + kq * 4);
                As[kq * 4 + 0][m] = av.x; As[kq * 4 + 1][m] = av.y;
                As[kq * 4 + 2][m] = av.z; As[kq * 4 + 3][m] = av.w;
                float4 bv = *(const float4*)(Wih + (size_t)(g0 + m) * WD + k0 + kq * 4);
                Bs[kq * 4 + 0][m] = bv.x; Bs[kq * 4 + 1][m] = bv.y;
                Bs[kq * 4 + 2][m] = bv.z; Bs[kq * 4 + 3][m] = bv.w;
            }
            __syncthreads();
#pragma unroll
            for (int kk = 0; kk < 16; ++kk) {
                float4 a0 = *(const float4*)&As[kk][tm * 8];
                float4 a1 = *(const float4*)&As[kk][tm * 8 + 4];
                float4 b0 = *(const float4*)&Bs[kk][tn * 8];
                float4 b1 = *(const float4*)&Bs[kk][tn * 8 + 4];
                float av8[8] = {a0.x, a0.y, a0.z, a0.w, a1.x, a1.y, a1.z, a1.w};
                float bv8[8] = {b0.x, b0.y, b0.z, b0.w, b1.x, b1.y, b1.z, b1.w};
#pragma unroll
                for (int a = 0; a < 8; a++)
#pragma unroll
                    for (int b = 0; b < 8; b++) acc[a][b] += av8[a] * bv8[b];
            }
            __syncthreads();
        }
        float bias[8];
#pragma unroll
        for (int b = 0; b < 8; b++) { int g = g0 + tn * 8 + b; bias[b] = bih[g] + bhh[g]; }
#pragma unroll
        for (int a = 0; a < 8; a++) {
            const int t = t0 + tm * 8 + a;
            float* op = zin + (size_t)t * G4 + g0 + tn * 8;
            f4 o0 = {acc[a][0] + bias[0], acc[a][1] + bias[1], acc[a][2] + bias[2], acc[a][3] + bias[3]};
            f4 o1 = {acc[a][4] + bias[4], acc[a][5] + bias[5], acc[a][6] + bias[6], acc[a][7] + bias[7]};
            asm volatile("global_store_dwordx4 %0, %1, off sc1" :: "v"(op), "v"(o0) : "memory");
            asm volatile("global_store_dwordx4 %0, %1, off sc1" :: "v"(op + 4), "v"(o1) : "memory");
        }
        __syncthreads();
        if (tid == 0) atomicAdd(&zcnt[dirn * 16 + ty], 1u);
        return;
    }

    if (role == 576) {
        // ================= VITERBI role (R7 logic, in-kernel) =================
        float* fs = (float*)SMEM;                                 // 40960 B
        unsigned short* par = (unsigned short*)(SMEM + 40960);    //  4096 B
        unsigned int* maps = (unsigned int*)(SMEM + 45056);       //   256 B
        int* bidx = (int*)(SMEM + 45312);                         //   256 B

        if (tid == 0) {     // wait for all 256 feats waves (counter ends at 255)
            const unsigned int* fp = &ctl[12];
            unsigned int cv;
            do {
                asm volatile("global_load_dword %0, %1, off sc0 sc1\n\t"
                             "s_waitcnt vmcnt(0)" : "=v"(cv) : "v"(fp) : "memory");
            } while (cv != 255u);
        }
        __syncthreads();
        for (int mm = 0; mm < 10; ++mm) {       // 256 thr x 40 floats = TT*NC
            const float* sp2 = feats + tid * 40 + mm * 4;
            f4 v;
            asm volatile("global_load_dwordx4 %0, %1, off sc0 sc1\n\t"
                         "s_waitcnt vmcnt(0)" : "=v"(v) : "v"(sp2) : "memory");
            *(f4*)(fs + tid * 40 + mm * 4) = v;
        }
        __syncthreads();

        float best = 0.f; int idx0 = 0;
        if (tid < 64) {
            float tr[25];
#pragma unroll
            for (int i = 0; i < 25; i++) tr[i] = trans[i];
            float layer[NC];
#pragma unroll
            for (int i = 0; i < NC; i++) layer[i] = fs[i] + tr[i * 5 + 3];
            float ftc[NC];
#pragma unroll
            for (int i = 0; i < NC; i++) ftc[i] = fs[1 * NC + i];
            for (int s = 0; s < TT - 1; ++s) {
                const int sp = (s + 2 < TT) ? (s + 2) : (TT - 1);
                float ftn[NC];
#pragma unroll
                for (int i = 0; i < NC; i++) ftn[i] = fs[sp * NC + i];
                float nl[NC]; int pk = 0;
#pragma unroll
                for (int i = 0; i < NC; i++) {
                    float b2 = tr[i * 5 + 0] + layer[0]; int bj = 0;
#pragma unroll
                    for (int jj = 1; jj < NC; jj++) {
                        const float v = tr[i * 5 + jj] + layer[jj];
                        if (v > b2) { b2 = v; bj = jj; }
                    }
                    nl[i] = ftc[i] + b2;
                    pk |= bj << (3 * i);
                }
#pragma unroll
                for (int i = 0; i < NC; i++) { layer[i] = nl[i]; ftc[i] = ftn[i]; }
                if (tid == 0) par[s] = (unsigned short)pk;
            }
            best = layer[0] + tr[20]; idx0 = 0;
#pragma unroll
            for (int jj = 1; jj < NC; jj++) {
                const float v = layer[jj] + tr[20 + jj];
                if (v > best) { best = v; idx0 = jj; }
            }
        }
        __syncthreads();

        int preg[32]; int slo = 0, shi = 0;
        if (tid < 64) {
            slo = tid * 32;
            const int shi0 = slo + 31;
            shi = (shi0 < TT - 1) ? shi0 : (TT - 2);
#pragma unroll
            for (int u = 0; u < 32; ++u) {
                int su = slo + u; if (su > TT - 2) su = TT - 2;
                preg[u] = (int)par[su];
            }
            int m0 = 0, m1 = 1, m2 = 2, m3 = 3, m4 = 4;
            for (int s = shi; s >= slo; --s) {
                const int pv = preg[s - slo];
                m0 = (pv >> (3 * m0)) & 7;
                m1 = (pv >> (3 * m1)) & 7;
                m2 = (pv >> (3 * m2)) & 7;
                m3 = (pv >> (3 * m3)) & 7;
                m4 = (pv >> (3 * m4)) & 7;
            }
            maps[tid] = (unsigned)(m0 | (m1 << 3) | (m2 << 6) | (m3 << 9) | (m4 << 12));
        }
        __syncthreads();
        if (tid == 0) {
            int e = idx0;
            for (int cc = 63; cc >= 0; --cc) {
                bidx[cc] = e;
                e = (int)((maps[cc] >> (3 * e)) & 7u);
            }
        }
        __syncthreads();
        if (tid < 64) {
            int e = bidx[tid];
            for (int s = shi; s >= slo; --s) {
                e = (preg[s - slo] >> (3 * e)) & 7;
                out[s] = (float)e;
            }
        }
        if (tid == 0) { out[TT - 1] = (float)idx0; out[TT] = best; }
        return;
    }
    if (role > 576) return;

    // ================= LSTM role (R0 verbatim + fast-path probe) =============
    float* hs = (float*)SMEM;                       // 2048 B
    float* zb = (float*)(SMEM + 2048);              // 1024 B
    const int d = role >> 5;          // 0 fwd, 1 bwd
    const int k = role & 31;
    const float* zin = d ? zin_b : zin_f;
    const float* Whh = d ? Whh_b : Whh_f;
    unsigned int* hw  = d ? hw_b  : hw_f;
    unsigned int* hwl = d ? hwl_b : hwl_f;

    const int q = tid >> 6;          // wave = column segment (128 cols)
    const int r = tid & 63;          // gate row within wg
    const int gate = r >> 4, jj = r & 15;
    const int grow = gate * HH + k * 16 + jj;      // global gate row [0,2048)

    const f4* wp = (const f4*)(Whh + (size_t)grow * HH + q * 128);
    f4 w[32];
#pragma unroll
    for (int i = 0; i < 32; ++i) w[i] = wp[i];     // plain loads: correct waitcnt
#pragma unroll
    for (int i = 0; i < 32; ++i)
        asm volatile("" : "+a"(w[i]));             // home the values in AGPRs

    float c = 0.f;
    const int l = tid;               // wave0 lane id (used when tid<64)
    const int g = l >> 4, j = l & 15;     // gate / unit for gate phase
    const int n16 = k * 16 + j;           // hidden index for gate phase

    int readyty = -1;                // last verified zin tile (wave0 only)
    int fastok = 1;                  // per-lane persistent fast-path enable

#define OK8 (a0.x != SENT && a0.y != SENT && a0.z != SENT && a0.w != SENT && \
             a1.x != SENT && a1.y != SENT && a1.z != SENT && a1.w != SENT)

    for (int it = 0; it < TT; ++it) {
        const int t = d ? (TT - 1 - it) : it;

        // wave0: zin value for (gate g, unit j) — issued before the poll
        float z = 0.f;
        if (tid < 64) {
            const int tyc = t >> 7;
            if (tyc != readyty) {            // once per 128 steps, wave-uniform
                const unsigned int* cp = zcnt + d * 16 + tyc;
                unsigned int cv;
                do {
                    asm volatile("global_load_dword %0, %1, off sc0 sc1\n\t"
                                 "s_waitcnt vmcnt(0)"
                                 : "=v"(cv) : "v"(cp) : "memory");
                } while (cv < 16u);
                readyty = tyc;
            }
            z = zin[(size_t)t * G4 + g * HH + n16];
        }

        if (it > 0 && tid < 64) {
            const int tp = d ? (t + 1) : (t - 1);
            const unsigned int* pa = hw  + (size_t)tp * HH + l * 8;
            u4 a0, a1;
            bool got = false;
            if (fastok && it > 4) {
                // nt probe: L1 no-allocate/evict -> respins reach the XCD L2,
                // where same-XCD producers' plain stores land write-through.
                const unsigned int* pl = hwl + (size_t)tp * HH + l * 8;
                int spins = 0;
                for (;;) {
                    asm volatile(
                        "global_load_dwordx4 %0, %2, off sc0 nt\n\t"
                        "global_load_dwordx4 %1, %2, off offset:16 sc0 nt\n\t"
                        "s_waitcnt vmcnt(0)"
                        : "=v"(a0), "=v"(a1) : "v"(pl) : "memory");
                    if (OK8) { got = true; break; }
                    if (++spins > 24) { fastok = 0; break; }   // permanent revert
                }
            }
            if (!got) {
                for (;;) {                     // R0-proven base probe
                    asm volatile(
                        "global_load_dwordx4 %0, %2, off sc0 sc1\n\t"
                        "global_load_dwordx4 %1, %2, off offset:16 sc0 sc1\n\t"
                        "s_waitcnt vmcnt(0)"
                        : "=v"(a0), "=v"(a1) : "v"(pa) : "memory");
                    if (OK8) break;
                }
            }
            u4* hd = (u4*)(hs + l * 8);
            hd[0] = a0; hd[1] = a1;
        }
        __syncthreads();                                   // B1: hs ready

        // keep weights homed in AGPRs across the loop (re-pin each iter)
#pragma unroll
        for (int i = 0; i < 32; ++i) asm volatile("" : "+a"(w[i]));

        float part = 0.f;
        if (it > 0) {
            const f4* hv = ((const f4*)hs) + (q << 5);     // wave-uniform broadcast
#pragma unroll
            for (int i = 0; i < 32; ++i) {
                f4 h4 = hv[i];
                part += w[i].x * h4.x + w[i].y * h4.y + w[i].z * h4.z + w[i].w * h4.w;
            }
        }
        zb[tid] = part;                                    // zb[q*64 + r]
        __syncthreads();                                   // B2: partials ready

        if (tid < 64) {
            // same summation order as R0 (bit-exact): qq = 0..3
            float s = zb[l] + zb[64 + l] + zb[128 + l] + zb[192 + l];
            const float pre = z + s;
            float act;
            if (g == 2) act = tanhf(pre);                  // g gate
            else        act = 1.f / (1.f + expf(-pre));    // i, f, o gates
            const float gi = __shfl(act, j);
            const float gf = __shfl(act, j + 16);
            const float gg = __shfl(act, j + 32);
            const float go = __shfl(act, j + 48);
            if (l < 16) {
                c = gf * c + gi * gg;
                const float hval = go * tanhf(c);
                const unsigned int hvbits = __float_as_uint(hval);
                unsigned int* hp  = &hw [(size_t)t * HH + k * 16 + l];
                unsigned int* hlp = &hwl[(size_t)t * HH + k * 16 + l];
                // dual store: plain -> local XCD L2 (fast path);
                //             sc1   -> LLC (R0-proven base path).
                asm volatile(
                    "global_store_dword %0, %2, off\n\t"
                    "global_store_dword %1, %2, off sc1"
                    :: "v"(hlp), "v"(hp), "v"(hvbits) : "memory");
            }
        }
        // 2 barriers suffice (see R0 comments).
    }
#undef OK8

    // ================= feats tail (R7, + sc1 stores & done-counter) ==========
    {
        const int wgid = d * 32 + k;
        float* const rowbuf = (float*)(SMEM + 3072) + q * 1024;
        for (int n = 0; n < 8; ++n) {
            const int t = (wgid * 4 + q) * 8 + n;
            {
                const unsigned int* pa = hw_f + (size_t)t * HH + r * 8;
                u4 a0, a1;
                for (;;) {
                    asm volatile(
                        "global_load_dwordx4 %0, %2, off sc0 sc1\n\t"
                        "global_load_dwordx4 %1, %2, off offset:16 sc0 sc1\n\t"
                        "s_waitcnt vmcnt(0)"
                        : "=v"(a0), "=v"(a1) : "v"(pa) : "memory");
                    if (a0.x != SENT && a0.y != SENT && a0.z != SENT && a0.w != SENT &&
                        a1.x != SENT && a1.y != SENT && a1.z != SENT && a1.w != SENT) break;
                }
                u4* dstp = (u4*)(rowbuf + r * 8);
                dstp[0] = a0; dstp[1] = a1;
            }
            {
                const unsigned int* pa = hw_b + (size_t)t * HH + r * 8;
                u4 a0, a1;
                for (;;) {
                    asm volatile(
                        "global_load_dwordx4 %0, %2, off sc0 sc1\n\t"
                        "global_load_dwordx4 %1, %2, off offset:16 sc0 sc1\n\t"
                        "s_waitcnt vmcnt(0)"
                        : "=v"(a0), "=v"(a1) : "v"(pa) : "memory");
                    if (a0.x != SENT && a0.y != SENT && a0.z != SENT && a0.w != SENT &&
                        a1.x != SENT && a1.y != SENT && a1.z != SENT && a1.w != SENT) break;
                }
                u4* dstp = (u4*)(rowbuf + HH + r * 8);
                dstp[0] = a0; dstp[1] = a1;
            }
            float facc[NC] = {0.f, 0.f, 0.f, 0.f, 0.f};
            for (int m = 0; m < 16; ++m) {
                const int cg = r + m * 64;
                const float hv = rowbuf[cg];
#pragma unroll
                for (int i = 0; i < NC; i++) facc[i] += hv * fc_w[i * (2 * HH) + cg];
            }
#pragma unroll
            for (int i = 0; i < NC; i++) {
#pragma unroll
                for (int off = 32; off; off >>= 1) facc[i] += __shfl_xor(facc[i], off);
            }
            if (r == 0) {
#pragma unroll
                for (int i = 0; i < NC; i++) {
                    const float fv = facc[i] + fc_b[i];
                    float* fp2 = feats + (size_t)t * NC + i;
                    asm volatile("global_store_dword %0, %1, off sc1"
                                 :: "v"(fp2), "v"(fv) : "memory");
                }
            }
        }
        asm volatile("s_waitcnt vmcnt(0)" ::: "memory");
        if (r == 0) atomicAdd(&ctl[12], 1u);   // 64 wgs x 4 waves = 256 -> 255
    }
}

// ---------------------------------------------------------------------------
extern "C" void kernel_launch(void* const* d_in, const int* in_sizes, int n_in,
                              void* d_out, int out_size, void* d_ws, size_t ws_size,
                              hipStream_t stream) {
    const int*   sent   = (const int*)d_in[0];
    const float* emb    = (const float*)d_in[1];
    const float* Wih_f  = (const float*)d_in[2];
    const float* Whh_f  = (const float*)d_in[3];
    const float* bih_f  = (const float*)d_in[4];
    const float* bhh_f  = (const float*)d_in[5];
    const float* Wih_b  = (const float*)d_in[6];
    const float* Whh_b  = (const float*)d_in[7];
    const float* bih_b  = (const float*)d_in[8];
    const float* bhh_b  = (const float*)d_in[9];
    const float* fc_w   = (const float*)d_in[10];
    const float* fc_b   = (const float*)d_in[11];
    const float* trans  = (const float*)d_in[12];
    float* out = (float*)d_out;

    char* ws = (char*)d_ws;
    float* zin_f = (float*)ws;                                    // 16 MB @ 0
    float* zin_b = (float*)(ws + (size_t)16777216);               // 16 MB @ 16M
    unsigned int* hw_f  = (unsigned int*)(ws + (size_t)33554432); //  4 MB @ 32M
    unsigned int* hw_b  = (unsigned int*)(ws + (size_t)37748736); //  4 MB @ 36M
    unsigned int* hwl_f = (unsigned int*)(ws + (size_t)41943040); //  4 MB @ 40M
    unsigned int* hwl_b = (unsigned int*)(ws + (size_t)46137344); //  4 MB @ 44M
    float* feats = (float*)(ws + (size_t)50331648);               // 40 KB @ 48M
    unsigned int* zcnt = (unsigned int*)(ws + (size_t)50397184);  // 128 B @ 48M+64K
    unsigned int* ctl  = (unsigned int*)(ws + (size_t)50397312);  // 128 B after zcnt

    // OWN the sentinel: hw_* and hwl_* = 0xFFFFFFFF (contiguous 16 MB @32M)
    hipMemsetAsync(hw_f, 0xFF, (size_t)16777216, stream);
    hipMemsetAsync(zcnt, 0, (size_t)128, stream);                 // zin tile flags
    hipMemsetAsync(ctl, 0xFF, (size_t)128, stream);               // claim control

    fused_all<<<577, 256, 0, stream>>>(sent, emb,
                                       Wih_f, bih_f, bhh_f,
                                       Wih_b, bih_b, bhh_b,
                                       Whh_f, Whh_b,
                                       zin_f, zin_b, hw_f, hw_b, hwl_f, hwl_b,
                                       zcnt, ctl, fc_w, fc_b, feats, trans, out);
}

// Round 10
// 4690.782 us; speedup vs baseline: 2.6776x; 2.6776x over previous
//
#include <hip/hip_runtime.h>

#define TT 2048
#define WD 768
#define HH 512
#define G4 2048      // 4*H
#define NC 5
#define SENT 0xFFFFFFFFu   // owned sentinel (-NaN); |h|<1 can never produce it.
                           // h buffers memset to 0xFF at every launch.

typedef float f4 __attribute__((ext_vector_type(4)));
typedef unsigned int u4 __attribute__((ext_vector_type(4)));

// ---------------------------------------------------------------------------
// FUSED kernel: 576 wgs — R7 VERBATIM (4063 us proven). R8's launch_bounds
// (256,2) capped VGPR at 128 and spilled the lstm role's 128-AGPR weight
// array to scratch (12.5 ms); reverted. Only change vs R7: feats stored at
// stride 6 (feats6) so the viterbi scan can use 8B-aligned float2 LDS reads.
//   wgs   0..63 : LSTM recurrence, R0 protocol verbatim + zin tile-flag
//                 check + feats tail (proven sentinel polls, bit-exact dot).
//   wgs 64..575 : zin GEMM overlay (R6-proven), t-tiles fwd-asc / bwd-desc.
// ---------------------------------------------------------------------------
__global__ __launch_bounds__(256, 1) void fused_main(
    const int* __restrict__ sent, const float* __restrict__ emb,
    const float* __restrict__ Wih_f, const float* __restrict__ bih_f, const float* __restrict__ bhh_f,
    const float* __restrict__ Wih_b, const float* __restrict__ bih_b, const float* __restrict__ bhh_b,
    const float* __restrict__ Whh_f, const float* __restrict__ Whh_b,
    float* __restrict__ zin_f, float* __restrict__ zin_b,
    unsigned int* __restrict__ hw_f, unsigned int* __restrict__ hw_b,
    unsigned int* __restrict__ zcnt,
    const float* __restrict__ fc_w, const float* __restrict__ fc_b,
    float* __restrict__ feats6)
{
    __shared__ float As[16][128];
    __shared__ float Bs[16][128];
    __shared__ float hs[HH];
    __shared__ float zb[256];

    const int tid = threadIdx.x;

    if (blockIdx.x >= 64) {
        // ================= GEMM role (R6 verbatim) =================
        const int lin  = blockIdx.x - 64;      // [0,512)
        const int pair = lin >> 5;             // [0,16): production order
        const int sub  = lin & 31;
        const int dirn = sub & 1;
        const int gx   = sub >> 1;             // [0,16)
        const int ty   = dirn ? (15 - pair) : pair;   // bwd consumes high t first

        const float* Wih = dirn ? Wih_b : Wih_f;
        const float* bih = dirn ? bih_b : bih_f;
        const float* bhh = dirn ? bhh_b : bhh_f;
        float* zin = dirn ? zin_b : zin_f;

        const int t0 = ty * 128;
        const int g0 = gx * 128;
        const int tm = tid >> 4, tn = tid & 15;

        float acc[8][8];
#pragma unroll
        for (int a = 0; a < 8; a++)
#pragma unroll
            for (int b = 0; b < 8; b++) acc[a][b] = 0.f;

        for (int kt = 0; kt < 48; ++kt) {
            const int k0 = kt * 16;
#pragma unroll
            for (int u = 0; u < 2; ++u) {
                const int s = tid * 2 + u;
                const int m = s >> 2, kq = s & 3;
                const int rowA = sent[t0 + m];
                float4 av = *(const float4*)(emb + (size_t)rowA * WD + k0 + kq * 4);
                As[kq * 4 + 0][m] = av.x; As[kq * 4 + 1][m] = av.y;
                As[kq * 4 + 2][m] = av.z; As[kq * 4 + 3][m] = av.w;
                float4 bv = *(const float4*)(Wih + (size_t)(g0 + m) * WD + k0 + kq * 4);
                Bs[kq * 4 + 0][m] = bv.x; Bs[kq * 4 + 1][m] = bv.y;
                Bs[kq * 4 + 2][m] = bv.z; Bs[kq * 4 + 3][m] = bv.w;
            }
            __syncthreads();
#pragma unroll
            for (int kk = 0; kk < 16; ++kk) {
                float4 a0 = *(const float4*)&As[kk][tm * 8];
                float4 a1 = *(const float4*)&As[kk][tm * 8 + 4];
                float4 b0 = *(const float4*)&Bs[kk][tn * 8];
                float4 b1 = *(const float4*)&Bs[kk][tn * 8 + 4];
                float av8[8] = {a0.x, a0.y, a0.z, a0.w, a1.x, a1.y, a1.z, a1.w};
                float bv8[8] = {b0.x, b0.y, b0.z, b0.w, b1.x, b1.y, b1.z, b1.w};
#pragma unroll
                for (int a = 0; a < 8; a++)
#pragma unroll
                    for (int b = 0; b < 8; b++) acc[a][b] += av8[a] * bv8[b];
            }
            __syncthreads();
        }
        float bias[8];
#pragma unroll
        for (int b = 0; b < 8; b++) { int g = g0 + tn * 8 + b; bias[b] = bih[g] + bhh[g]; }
#pragma unroll
        for (int a = 0; a < 8; a++) {
            const int t = t0 + tm * 8 + a;
            float* op = zin + (size_t)t * G4 + g0 + tn * 8;
            f4 o0 = {acc[a][0] + bias[0], acc[a][1] + bias[1], acc[a][2] + bias[2], acc[a][3] + bias[3]};
            f4 o1 = {acc[a][4] + bias[4], acc[a][5] + bias[5], acc[a][6] + bias[6], acc[a][7] + bias[7]};
            // sc1: write-through to LLC (within-kernel cross-XCD visibility)
            asm volatile("global_store_dwordx4 %0, %1, off sc1" :: "v"(op), "v"(o0) : "memory");
            asm volatile("global_store_dwordx4 %0, %1, off sc1" :: "v"(op + 4), "v"(o1) : "memory");
        }
        __syncthreads();    // per-wave vmcnt(0) drain precedes the barrier
        if (tid == 0) atomicAdd(&zcnt[dirn * 16 + ty], 1u);   // device-scope
        return;
    }

    // ================= LSTM role (R0 verbatim + tile-flag check) =================
    const int bid = blockIdx.x;
    const int d = bid >> 5;          // 0 fwd, 1 bwd
    const int k = bid & 31;
    const float* zin = d ? zin_b : zin_f;
    const float* Whh = d ? Whh_b : Whh_f;
    unsigned int* hw = d ? hw_b : hw_f;

    const int q = tid >> 6;          // wave = column segment (128 cols)
    const int r = tid & 63;          // gate row within wg
    const int gate = r >> 4, jj = r & 15;
    const int grow = gate * HH + k * 16 + jj;      // global gate row [0,2048)

    const f4* wp = (const f4*)(Whh + (size_t)grow * HH + q * 128);
    f4 w[32];
#pragma unroll
    for (int i = 0; i < 32; ++i) w[i] = wp[i];     // plain loads: correct waitcnt
#pragma unroll
    for (int i = 0; i < 32; ++i)
        asm volatile("" : "+a"(w[i]));             // home the values in AGPRs

    float c = 0.f;
    const int l = tid;               // wave0 lane id (used when tid<64)
    const int g = l >> 4, j = l & 15;     // gate / unit for gate phase
    const int n16 = k * 16 + j;           // hidden index for gate phase

    int readyty = -1;                // last verified zin tile (wave0 only)

    for (int it = 0; it < TT; ++it) {
        const int t = d ? (TT - 1 - it) : it;

        // wave0: zin value for (gate g, unit j) — issued before the poll
        float z = 0.f;
        if (tid < 64) {
            const int tyc = t >> 7;
            if (tyc != readyty) {            // once per 128 steps, wave-uniform
                const unsigned int* cp = zcnt + d * 16 + tyc;
                unsigned int cv;
                do {
                    asm volatile("global_load_dword %0, %1, off sc0 sc1\n\t"
                                 "s_waitcnt vmcnt(0)"
                                 : "=v"(cv) : "v"(cp) : "memory");
                } while (cv < 16u);
                readyty = tyc;
            }
            z = zin[(size_t)t * G4 + g * HH + n16];
        }

        if (it > 0 && tid < 64) {
            const int tp = d ? (t + 1) : (t - 1);
            const unsigned int* pa = hw + (size_t)tp * HH + l * 8;
            u4 a0, a1;
            for (;;) {
                asm volatile(
                    "global_load_dwordx4 %0, %2, off sc0 sc1\n\t"
                    "global_load_dwordx4 %1, %2, off offset:16 sc0 sc1\n\t"
                    "s_waitcnt vmcnt(0)"
                    : "=v"(a0), "=v"(a1) : "v"(pa) : "memory");
                if (a0.x != SENT && a0.y != SENT && a0.z != SENT && a0.w != SENT &&
                    a1.x != SENT && a1.y != SENT && a1.z != SENT && a1.w != SENT) break;
            }
            u4* hd = (u4*)(hs + l * 8);
            hd[0] = a0; hd[1] = a1;
        }
        __syncthreads();                                   // B1: hs ready

        // keep weights homed in AGPRs across the loop (re-pin each iter)
#pragma unroll
        for (int i = 0; i < 32; ++i) asm volatile("" : "+a"(w[i]));

        float part = 0.f;
        if (it > 0) {
            const f4* hv = ((const f4*)hs) + (q << 5);     // wave-uniform broadcast
#pragma unroll
            for (int i = 0; i < 32; ++i) {
                f4 h4 = hv[i];
                part += w[i].x * h4.x + w[i].y * h4.y + w[i].z * h4.z + w[i].w * h4.w;
            }
        }
        zb[tid] = part;                                    // zb[q*64 + r]
        __syncthreads();                                   // B2: partials ready

        if (tid < 64) {
            // same summation order as R0 (bit-exact): qq = 0..3
            float s = zb[l] + zb[64 + l] + zb[128 + l] + zb[192 + l];
            const float pre = z + s;
            float act;
            if (g == 2) act = tanhf(pre);                  // g gate
            else        act = 1.f / (1.f + expf(-pre));    // i, f, o gates
            const float gi = __shfl(act, j);
            const float gf = __shfl(act, j + 16);
            const float gg = __shfl(act, j + 32);
            const float go = __shfl(act, j + 48);
            if (l < 16) {
                c = gf * c + gi * gg;
                const float hval = go * tanhf(c);
                __hip_atomic_store(&hw[(size_t)t * HH + k * 16 + l],
                                   __float_as_uint(hval),
                                   __ATOMIC_RELAXED, __HIP_MEMORY_SCOPE_AGENT);
            }
        }
        // 2 barriers suffice (see R0 comments).
    }

    // ================= feats tail (R7 verbatim, stride-6 stores) =============
    {
        const int wgid = d * 32 + k;
        float* const rowbuf = (q < 2) ? (&As[0][0] + q * 1024)
                                      : (&Bs[0][0] + (q - 2) * 1024);
        for (int n = 0; n < 8; ++n) {
            const int t = (wgid * 4 + q) * 8 + n;
            {
                const unsigned int* pa = hw_f + (size_t)t * HH + r * 8;
                u4 a0, a1;
                for (;;) {
                    asm volatile(
                        "global_load_dwordx4 %0, %2, off sc0 sc1\n\t"
                        "global_load_dwordx4 %1, %2, off offset:16 sc0 sc1\n\t"
                        "s_waitcnt vmcnt(0)"
                        : "=v"(a0), "=v"(a1) : "v"(pa) : "memory");
                    if (a0.x != SENT && a0.y != SENT && a0.z != SENT && a0.w != SENT &&
                        a1.x != SENT && a1.y != SENT && a1.z != SENT && a1.w != SENT) break;
                }
                u4* dstp = (u4*)(rowbuf + r * 8);
                dstp[0] = a0; dstp[1] = a1;
            }
            {
                const unsigned int* pa = hw_b + (size_t)t * HH + r * 8;
                u4 a0, a1;
                for (;;) {
                    asm volatile(
                        "global_load_dwordx4 %0, %2, off sc0 sc1\n\t"
                        "global_load_dwordx4 %1, %2, off offset:16 sc0 sc1\n\t"
                        "s_waitcnt vmcnt(0)"
                        : "=v"(a0), "=v"(a1) : "v"(pa) : "memory");
                    if (a0.x != SENT && a0.y != SENT && a0.z != SENT && a0.w != SENT &&
                        a1.x != SENT && a1.y != SENT && a1.z != SENT && a1.w != SENT) break;
                }
                u4* dstp = (u4*)(rowbuf + HH + r * 8);
                dstp[0] = a0; dstp[1] = a1;
            }
            float facc[NC] = {0.f, 0.f, 0.f, 0.f, 0.f};
            for (int m = 0; m < 16; ++m) {
                const int cg = r + m * 64;
                const float hv = rowbuf[cg];   // [h_f | h_b] layout, bit-exact
#pragma unroll
                for (int i = 0; i < NC; i++) facc[i] += hv * fc_w[i * (2 * HH) + cg];
            }
#pragma unroll
            for (int i = 0; i < NC; i++) {
#pragma unroll
                for (int off = 32; off; off >>= 1) facc[i] += __shfl_xor(facc[i], off);
            }
            if (r == 0) {
#pragma unroll
                for (int i = 0; i < NC; i++)
                    feats6[(size_t)t * 6 + i] = facc[i] + fc_b[i];   // stride 6
            }
        }
    }
}

// ---------------------------------------------------------------------------
// Viterbi: R8 gap analysis (one-kernel total-dispatch = 25 us) pins this
// kernel at ~640 us in R7 = ~750 cy/step — latency-serialized LDS round
// trips on the forward scan's dependent chain. Fix: feats staged in LDS at
// stride 6 (8B-aligned float2 reads), scan blocked x8 with all 24 reads
// batched per block (one lgkmcnt region amortized over 8 pure-VALU steps).
// Per-step arithmetic order IDENTICAL to R0-R7 (bit-exact path + score).
// Backtrack: R7's integer-exact parallel version, writing out directly.
// ---------------------------------------------------------------------------
__global__ void viterbi_kernel(const float* __restrict__ feats6,
                               const float* __restrict__ trans,
                               float* __restrict__ out)
{
    __shared__ float fs6[TT * 6];              // 49152 B
    __shared__ unsigned short par[TT];         //  4096 B
    __shared__ unsigned int maps[64];
    __shared__ int bidx[64];
    const int tid = threadIdx.x;

    for (int i = tid; i < TT * 6 / 4; i += 64)
        ((f4*)fs6)[i] = ((const f4*)feats6)[i];
    float tr[25];
#pragma unroll
    for (int i = 0; i < 25; i++) tr[i] = trans[i];
    __syncthreads();

    float layer[NC];
#pragma unroll
    for (int i = 0; i < NC; i++) layer[i] = fs6[i] + tr[i * 5 + 3];

    // ---- forward scan: 255 blocks of 8 steps + 7-step tail (2047 steps) ----
    for (int b = 0; b < 255; ++b) {
        const int s0 = b * 8;
        float2 fb[8][3];
#pragma unroll
        for (int u = 0; u < 8; ++u) {
            const float2* fp = (const float2*)(fs6 + (size_t)(s0 + u + 1) * 6);
            fb[u][0] = fp[0]; fb[u][1] = fp[1]; fb[u][2] = fp[2];
        }
#pragma unroll
        for (int u = 0; u < 8; ++u) {
            const float ft[NC] = {fb[u][0].x, fb[u][0].y, fb[u][1].x, fb[u][1].y, fb[u][2].x};
            float nl[NC]; int pk = 0;
#pragma unroll
            for (int i = 0; i < NC; i++) {
                float best = tr[i * 5 + 0] + layer[0]; int bj = 0;
#pragma unroll
                for (int jj = 1; jj < NC; jj++) {
                    const float v = tr[i * 5 + jj] + layer[jj];
                    if (v > best) { best = v; bj = jj; }
                }
                nl[i] = ft[i] + best;
                pk |= bj << (3 * i);
            }
#pragma unroll
            for (int i = 0; i < NC; i++) layer[i] = nl[i];
            if (tid == 0) par[s0 + u] = (unsigned short)pk;
        }
    }
    for (int s = 2040; s < TT - 1; ++s) {      // tail
        const float* fp = fs6 + (size_t)(s + 1) * 6;
        const float ft[NC] = {fp[0], fp[1], fp[2], fp[3], fp[4]};
        float nl[NC]; int pk = 0;
#pragma unroll
        for (int i = 0; i < NC; i++) {
            float best = tr[i * 5 + 0] + layer[0]; int bj = 0;
#pragma unroll
            for (int jj = 1; jj < NC; jj++) {
                const float v = tr[i * 5 + jj] + layer[jj];
                if (v > best) { best = v; bj = jj; }
            }
            nl[i] = ft[i] + best;
            pk |= bj << (3 * i);
        }
#pragma unroll
        for (int i = 0; i < NC; i++) layer[i] = nl[i];
        if (tid == 0) par[s] = (unsigned short)pk;
    }

    float best = layer[0] + tr[20]; int idx0 = 0;
#pragma unroll
    for (int jj = 1; jj < NC; jj++) {
        const float v = layer[jj] + tr[20 + jj];
        if (v > best) { best = v; idx0 = jj; }
    }
    __syncthreads();

    // ---- parallel backtrack (integer-exact, R7 verbatim) ----
    const int slo = tid * 32;
    const int shi0 = slo + 31;
    const int shi = (shi0 < TT - 1) ? shi0 : (TT - 2);
    int preg[32];
#pragma unroll
    for (int u = 0; u < 32; ++u) {
        int su = slo + u; if (su > TT - 2) su = TT - 2;   // clamp (unused dups)
        preg[u] = (int)par[su];
    }
    int m0 = 0, m1 = 1, m2 = 2, m3 = 3, m4 = 4;
    for (int s = shi; s >= slo; --s) {
        const int pv = preg[s - slo];
        m0 = (pv >> (3 * m0)) & 7;
        m1 = (pv >> (3 * m1)) & 7;
        m2 = (pv >> (3 * m2)) & 7;
        m3 = (pv >> (3 * m3)) & 7;
        m4 = (pv >> (3 * m4)) & 7;
    }
    maps[tid] = (unsigned)(m0 | (m1 << 3) | (m2 << 6) | (m3 << 9) | (m4 << 12));
    __syncthreads();
    if (tid == 0) {
        int e = idx0;                     // idx entering chunk 63 (= idx_{TT-1})
        for (int cc = 63; cc >= 0; --cc) {
            bidx[cc] = e;
            e = (int)((maps[cc] >> (3 * e)) & 7u);
        }
    }
    __syncthreads();
    {
        int e = bidx[tid];
        for (int s = shi; s >= slo; --s) {
            e = (preg[s - slo] >> (3 * e)) & 7;
            out[s] = (float)e;
        }
    }
    if (tid == 0) { out[TT - 1] = (float)idx0; out[TT] = best; }
}

// ---------------------------------------------------------------------------
extern "C" void kernel_launch(void* const* d_in, const int* in_sizes, int n_in,
                              void* d_out, int out_size, void* d_ws, size_t ws_size,
                              hipStream_t stream) {
    const int*   sent   = (const int*)d_in[0];
    const float* emb    = (const float*)d_in[1];
    const float* Wih_f  = (const float*)d_in[2];
    const float* Whh_f  = (const float*)d_in[3];
    const float* bih_f  = (const float*)d_in[4];
    const float* bhh_f  = (const float*)d_in[5];
    const float* Wih_b  = (const float*)d_in[6];
    const float* Whh_b  = (const float*)d_in[7];
    const float* bih_b  = (const float*)d_in[8];
    const float* bhh_b  = (const float*)d_in[9];
    const float* fc_w   = (const float*)d_in[10];
    const float* fc_b   = (const float*)d_in[11];
    const float* trans  = (const float*)d_in[12];
    float* out = (float*)d_out;

    char* ws = (char*)d_ws;
    float* zin_f = (float*)ws;                                   // 16 MB @ 0
    float* zin_b = (float*)(ws + (size_t)16777216);              // 16 MB @ 16M
    unsigned int* hw_f = (unsigned int*)(ws + (size_t)33554432); //  4 MB @ 32M
    unsigned int* hw_b = (unsigned int*)(ws + (size_t)37748736); //  4 MB @ 36M
    float* feats6 = (float*)(ws + (size_t)41943040);             // 48 KB @ 40M (stride 6)
    unsigned int* zcnt = (unsigned int*)(ws + (size_t)42008576); // 128 B @ 40M+64K

    // OWN the sentinel: h buffers = 0xFFFFFFFF (-NaN, impossible h)
    hipMemsetAsync(hw_f, 0xFF, (size_t)8388608, stream);         // covers hw_f + hw_b
    hipMemsetAsync(zcnt, 0, (size_t)128, stream);                // zin tile flags

    fused_main<<<576, 256, 0, stream>>>(sent, emb,
                                        Wih_f, bih_f, bhh_f,
                                        Wih_b, bih_b, bhh_b,
                                        Whh_f, Whh_b,
                                        zin_f, zin_b, hw_f, hw_b, zcnt,
                                        fc_w, fc_b, feats6);

    viterbi_kernel<<<1, 64, 0, stream>>>(feats6, trans, out);
}